// Round 8
// baseline (47.802 us; speedup 1.0000x reference)
//
#include <hip/hip_runtime.h>
#include <hip/hip_fp16.h>

#define NCLS 21
#define HW (512 * 512)
#define HW2 (HW / 2)                   // 131072 float2 per (b,c) plane
#define NB 8
#define NPIX (NB * HW)                 // 2097152
#define NPIX2 (NPIX / 2)               // 1048576 pixel-pairs
#define NPIX4 (NPIX / 4)               // 524288 pixel-quads
#define NBLK1 (NPIX2 / 256)            // 4096 blocks pass1
#define NBLK2 (NPIX4 / 256)            // 2048 blocks pass2
#define TOTAL_ELEMS ((long long)NPIX * NCLS)

// ws layout:
//   [0     .. 16K)  float bmin[4096]
//   [16K   .. 32K)  float bmax[4096]
//   [32K   .. 48K)  double partial[2048]
//   [64K   .. +8MB) packed half2 per pixel (x=sigma_raw fp16, y=S fp16)

union HU { __half2 h; unsigned int u; };

// Pass 1: float2 pixel-pairs; logits kept PACKED half2 in registers (21 VGPR
// instead of 42) -> <=64 VGPR -> 8 waves/SIMD. Single global read of logits.
__global__ __launch_bounds__(256, 8) void lasd_pass1(const float2* __restrict__ in2,
                                                     const int2* __restrict__ tgt2,
                                                     uint2* __restrict__ sigS2,
                                                     float* __restrict__ bmin,
                                                     float* __restrict__ bmax) {
    int j = blockIdx.x * 256 + threadIdx.x;    // pixel-pair index
    int b = j >> 17;                            // j / HW2
    int p2 = j & (HW2 - 1);
    const float2* base = in2 + ((size_t)(b * NCLS) << 17) + p2;

    unsigned int xh[NCLS];                      // packed half2 logits
    float s0 = 0.f, s1 = 0.f;
#pragma unroll
    for (int c = 0; c < NCLS; ++c) {
        float2 x = base[(size_t)c << 17];
        s0 += __expf(x.x);
        s1 += __expf(x.y);
        HU h; h.h = __floats2half2_rn(x.x, x.y);   // v_cvt_pkrtz
        xh[c] = h.u;
    }
    float inv0 = 1.0f / s0, inv1 = 1.0f / s1;
    float ls0 = __logf(s0), ls1 = __logf(s1);

    int2 tt = tgt2[j];

    float sp0 = 0, sp1 = 0, q0 = 0, q1 = 0, F0 = 0, F1 = 0, ft0 = 0, ft1 = 0;
#pragma unroll
    for (int c = 0; c < NCLS; ++c) {
        HU h; h.u = xh[c];
        float x0 = __low2float(h.h);
        float x1 = __high2float(h.h);
        float p0 = fmaf(__expf(x0), inv0, 1e-8f);        // softmax + EPS
        float p1 = fmaf(__expf(x1), inv1, 1e-8f);
        float om0 = 1.0f - p0, om1 = 1.0f - p1;
        float f0 = -0.25f * om0 * om0 * (x0 - ls0);      // log p = x - log s
        float f1 = -0.25f * om1 * om1 * (x1 - ls1);
        sp0 += p0; sp1 += p1;
        q0 = fmaf(p0, p0, q0); q1 = fmaf(p1, p1, q1);
        F0 += f0; F1 += f1;
        if (c == tt.x) ft0 = f0;
        if (c == tt.y) ft1 = f1;
    }

    float var0 = fmaxf(q0 - sp0 * sp0 * (1.0f / 21.0f), 0.0f);
    float var1 = fmaxf(q1 - sp1 * sp1 * (1.0f / 21.0f), 0.0f);
    float sg0 = sqrtf(var0 * (1.0f / 20.0f));            // ddof=1
    float sg1 = sqrtf(var1 * (1.0f / 20.0f));
    float S0 = ft0 + 1e-6f * F0;
    float S1 = ft1 + 1e-6f * F1;

    HU h0, h1;
    h0.h.x = __float2half_rn(sg0); h0.h.y = __float2half_rn(S0);
    h1.h.x = __float2half_rn(sg1); h1.h.y = __float2half_rn(S1);
    uint2 pk; pk.x = h0.u; pk.y = h1.u;
    sigS2[j] = pk;

    // min/max over the ROUNDED sigmas (consistent with what pass2 reads)
    float r0 = __half2float(h0.h.x), r1 = __half2float(h1.h.x);
    float lmin = fminf(r0, r1), lmax = fmaxf(r0, r1);
#pragma unroll
    for (int off = 32; off > 0; off >>= 1) {
        lmin = fminf(lmin, __shfl_down(lmin, off));
        lmax = fmaxf(lmax, __shfl_down(lmax, off));
    }
    __shared__ float smn[4], smx[4];
    int wid = threadIdx.x >> 6, lane = threadIdx.x & 63;
    if (lane == 0) { smn[wid] = lmin; smx[wid] = lmax; }
    __syncthreads();
    if (threadIdx.x == 0) {
        bmin[blockIdx.x] = fminf(fminf(smn[0], smn[1]), fminf(smn[2], smn[3]));
        bmax[blockIdx.x] = fmaxf(fmaxf(smx[0], smx[1]), fmaxf(smx[2], smx[3]));
    }
}

// Pass 2: redundant per-block min/max reduce (L2/L3-served, no fence);
// normalize sigma -> out; per-block beta*S partial sums.
__global__ __launch_bounds__(256) void lasd_pass2(const uint4* __restrict__ sigS4,
                                                  float* __restrict__ out,     // [1..] sigma
                                                  const float4* __restrict__ bmin4,
                                                  const float4* __restrict__ bmax4,
                                                  double* __restrict__ partial) {
    const int wid = threadIdx.x >> 6, lane = threadIdx.x & 63;

    float a = 1e30f, z = -1e30f;
#pragma unroll
    for (int k = 0; k < NBLK1 / 4 / 256; ++k) {          // 4096 floats = 1024 float4
        float4 v = bmin4[threadIdx.x + k * 256];
        float4 w = bmax4[threadIdx.x + k * 256];
        a = fminf(a, fminf(fminf(v.x, v.y), fminf(v.z, v.w)));
        z = fmaxf(z, fmaxf(fmaxf(w.x, w.y), fmaxf(w.z, w.w)));
    }
#pragma unroll
    for (int off = 32; off > 0; off >>= 1) {
        a = fminf(a, __shfl_down(a, off));
        z = fmaxf(z, __shfl_down(z, off));
    }
    __shared__ float smn[4], smx[4];
    __shared__ float s_min, s_rinv;
    if (lane == 0) { smn[wid] = a; smx[wid] = z; }
    __syncthreads();
    if (threadIdx.x == 0) {
        float mn = fminf(fminf(smn[0], smn[1]), fminf(smn[2], smn[3]));
        float mx = fmaxf(fmaxf(smx[0], smx[1]), fmaxf(smx[2], smx[3]));
        s_min = mn;
        s_rinv = 1.0f / (mx - mn);
    }
    __syncthreads();
    float smin = s_min, rinv = s_rinv;

    int j = blockIdx.x * 256 + threadIdx.x;              // pixel-quad index
    uint4 pk = sigS4[j];
    unsigned int w[4] = {pk.x, pk.y, pk.z, pk.w};
    float lsum = 0.0f;
#pragma unroll
    for (int k = 0; k < 4; ++k) {
        HU cv; cv.u = w[k];
        float sg = __half2float(cv.h.x);
        float S = __half2float(cv.h.y);
        float t = (sg - smin) * rinv;
        out[1 + 4 * j + k] = t;
        lsum += (__expf(-t) + 1.0f) * S;
    }
#pragma unroll
    for (int off = 32; off > 0; off >>= 1) lsum += __shfl_down(lsum, off);
    __shared__ float shs[4];
    if (lane == 0) shs[wid] = lsum;
    __syncthreads();
    if (threadIdx.x == 0)
        partial[blockIdx.x] = (double)(shs[0] + shs[1] + shs[2] + shs[3]);
}

// Final: sum 2048 doubles -> loss
__global__ __launch_bounds__(256) void lasd_finish(const double* __restrict__ partial,
                                                   float* __restrict__ loss_out) {
    double acc = 0.0;
#pragma unroll
    for (int k = 0; k < NBLK2 / 256; ++k)
        acc += partial[threadIdx.x + k * 256];
#pragma unroll
    for (int off = 32; off > 0; off >>= 1) acc += __shfl_down(acc, off);
    __shared__ double sh[4];
    int wid = threadIdx.x >> 6, lane = threadIdx.x & 63;
    if (lane == 0) sh[wid] = acc;
    __syncthreads();
    if (threadIdx.x == 0)
        loss_out[0] = (float)((sh[0] + sh[1] + sh[2] + sh[3]) / (double)TOTAL_ELEMS);
}

extern "C" void kernel_launch(void* const* d_in, const int* in_sizes, int n_in,
                              void* d_out, int out_size, void* d_ws, size_t ws_size,
                              hipStream_t stream) {
    const float2* logits2 = (const float2*)d_in[0];
    const int2* target2 = (const int2*)d_in[1];
    float* out = (float*)d_out;                  // out[0]=loss, out[1..]=sigma
    char* ws = (char*)d_ws;

    float* bmin = (float*)ws;                    // 4096 f
    float* bmax = (float*)(ws + 16384);          // 4096 f
    double* partial = (double*)(ws + 32768);     // 2048 d
    uint2* sigS = (uint2*)(ws + 65536);          // 8 MB packed

    lasd_pass1<<<NBLK1, 256, 0, stream>>>(logits2, target2, sigS, bmin, bmax);
    lasd_pass2<<<NBLK2, 256, 0, stream>>>((const uint4*)sigS, out,
                                          (const float4*)bmin, (const float4*)bmax,
                                          partial);
    lasd_finish<<<1, 256, 0, stream>>>(partial, out);
}

// Round 9
// 45.912 us; speedup vs baseline: 1.0412x; 1.0412x over previous
//
#include <hip/hip_runtime.h>
#include <hip/hip_fp16.h>

#define NCLS 21
#define HW (512 * 512)
#define NB 8
#define NPIX (NB * HW)                 // 2097152
#define NPIX4 (NPIX / 4)               // 524288 pixel-quads
#define NBLK1 (NPIX / 256)             // 8192 blocks pass1 (1 px/thread)
#define NBLK2 (NPIX4 / 256)            // 2048 blocks pass2
#define TOTAL_ELEMS ((long long)NPIX * NCLS)

// ws layout:
//   [0     .. 32K)  float bmin[8192]
//   [32K   .. 64K)  float bmax[8192]
//   [64K   .. 80K)  double partial[2048]
//   [128K  .. +8MB) packed half2 per pixel (x=sigma_raw fp16, y=S fp16)

union HU { __half2 h; unsigned int u; };

// Pass 1: ONE pixel per thread -> ~50 VGPR -> 8 waves/SIMD. Single logits
// read, scalar coalesced loads. Same math as the proven R6 kernel.
__global__ __launch_bounds__(256) void lasd_pass1(const float* __restrict__ in,
                                                  const int* __restrict__ tgt,
                                                  unsigned int* __restrict__ sigS,
                                                  float* __restrict__ bmin,
                                                  float* __restrict__ bmax) {
    int i = blockIdx.x * 256 + threadIdx.x;    // pixel index
    int b = i >> 18;                            // i / HW
    int pix = i & (HW - 1);
    const float* base = in + ((size_t)(b * NCLS) << 18) + pix;

    float x[NCLS];
    float s = 0.0f;
#pragma unroll
    for (int c = 0; c < NCLS; ++c) {
        x[c] = base[(size_t)c << 18];
        s += __expf(x[c]);
    }
    float inv = 1.0f / s;
    float ls = __logf(s);

    int t = tgt[i];

    float sp = 0.f, q = 0.f, F = 0.f, ft = 0.f;
#pragma unroll
    for (int c = 0; c < NCLS; ++c) {
        float p = fmaf(__expf(x[c]), inv, 1e-8f);       // softmax + EPS
        float om = 1.0f - p;
        float f = -0.25f * om * om * (x[c] - ls);       // log p = x - log s
        sp += p;
        q = fmaf(p, p, q);
        F += f;
        if (c == t) ft = f;
    }

    float var = fmaxf(q - sp * sp * (1.0f / 21.0f), 0.0f);
    float sg = sqrtf(var * (1.0f / 20.0f));             // ddof=1
    float S = ft + 1e-6f * F;

    HU h;
    h.h.x = __float2half_rn(sg);
    h.h.y = __float2half_rn(S);
    sigS[i] = h.u;

    // min/max over the ROUNDED sigma (consistent with what pass2 reads)
    float r = __half2float(h.h.x);
    float lmin = r, lmax = r;
#pragma unroll
    for (int off = 32; off > 0; off >>= 1) {
        lmin = fminf(lmin, __shfl_down(lmin, off));
        lmax = fmaxf(lmax, __shfl_down(lmax, off));
    }
    __shared__ float smn[4], smx[4];
    int wid = threadIdx.x >> 6, lane = threadIdx.x & 63;
    if (lane == 0) { smn[wid] = lmin; smx[wid] = lmax; }
    __syncthreads();
    if (threadIdx.x == 0) {
        bmin[blockIdx.x] = fminf(fminf(smn[0], smn[1]), fminf(smn[2], smn[3]));
        bmax[blockIdx.x] = fmaxf(fmaxf(smx[0], smx[1]), fmaxf(smx[2], smx[3]));
    }
}

// Pass 2: redundant per-block min/max reduce (L2/L3-served, no fence);
// normalize sigma -> out; per-block beta*S partial sums.
__global__ __launch_bounds__(256) void lasd_pass2(const uint4* __restrict__ sigS4,
                                                  float* __restrict__ out,     // [1..] sigma
                                                  const float4* __restrict__ bmin4,
                                                  const float4* __restrict__ bmax4,
                                                  double* __restrict__ partial) {
    const int wid = threadIdx.x >> 6, lane = threadIdx.x & 63;

    float a = 1e30f, z = -1e30f;
#pragma unroll
    for (int k = 0; k < NBLK1 / 4 / 256; ++k) {          // 8192 floats = 2048 float4
        float4 v = bmin4[threadIdx.x + k * 256];
        float4 w = bmax4[threadIdx.x + k * 256];
        a = fminf(a, fminf(fminf(v.x, v.y), fminf(v.z, v.w)));
        z = fmaxf(z, fmaxf(fmaxf(w.x, w.y), fmaxf(w.z, w.w)));
    }
#pragma unroll
    for (int off = 32; off > 0; off >>= 1) {
        a = fminf(a, __shfl_down(a, off));
        z = fmaxf(z, __shfl_down(z, off));
    }
    __shared__ float smn[4], smx[4];
    __shared__ float s_min, s_rinv;
    if (lane == 0) { smn[wid] = a; smx[wid] = z; }
    __syncthreads();
    if (threadIdx.x == 0) {
        float mn = fminf(fminf(smn[0], smn[1]), fminf(smn[2], smn[3]));
        float mx = fmaxf(fmaxf(smx[0], smx[1]), fmaxf(smx[2], smx[3]));
        s_min = mn;
        s_rinv = 1.0f / (mx - mn);
    }
    __syncthreads();
    float smin = s_min, rinv = s_rinv;

    int j = blockIdx.x * 256 + threadIdx.x;              // pixel-quad index
    uint4 pk = sigS4[j];
    unsigned int w[4] = {pk.x, pk.y, pk.z, pk.w};
    float lsum = 0.0f;
#pragma unroll
    for (int k = 0; k < 4; ++k) {
        HU cv; cv.u = w[k];
        float sg = __half2float(cv.h.x);
        float S = __half2float(cv.h.y);
        float t = (sg - smin) * rinv;
        out[1 + 4 * j + k] = t;
        lsum += (__expf(-t) + 1.0f) * S;
    }
#pragma unroll
    for (int off = 32; off > 0; off >>= 1) lsum += __shfl_down(lsum, off);
    __shared__ float shs[4];
    if (lane == 0) shs[wid] = lsum;
    __syncthreads();
    if (threadIdx.x == 0)
        partial[blockIdx.x] = (double)(shs[0] + shs[1] + shs[2] + shs[3]);
}

// Final: sum 2048 doubles -> loss
__global__ __launch_bounds__(256) void lasd_finish(const double* __restrict__ partial,
                                                   float* __restrict__ loss_out) {
    double acc = 0.0;
#pragma unroll
    for (int k = 0; k < NBLK2 / 256; ++k)
        acc += partial[threadIdx.x + k * 256];
#pragma unroll
    for (int off = 32; off > 0; off >>= 1) acc += __shfl_down(acc, off);
    __shared__ double sh[4];
    int wid = threadIdx.x >> 6, lane = threadIdx.x & 63;
    if (lane == 0) sh[wid] = acc;
    __syncthreads();
    if (threadIdx.x == 0)
        loss_out[0] = (float)((sh[0] + sh[1] + sh[2] + sh[3]) / (double)TOTAL_ELEMS);
}

extern "C" void kernel_launch(void* const* d_in, const int* in_sizes, int n_in,
                              void* d_out, int out_size, void* d_ws, size_t ws_size,
                              hipStream_t stream) {
    const float* logits = (const float*)d_in[0];
    const int* target = (const int*)d_in[1];
    float* out = (float*)d_out;                  // out[0]=loss, out[1..]=sigma
    char* ws = (char*)d_ws;

    float* bmin = (float*)ws;                    // 8192 f
    float* bmax = (float*)(ws + 32768);          // 8192 f
    double* partial = (double*)(ws + 65536);     // 2048 d
    unsigned int* sigS = (unsigned int*)(ws + 131072);   // 8 MB packed

    lasd_pass1<<<NBLK1, 256, 0, stream>>>(logits, target, sigS, bmin, bmax);
    lasd_pass2<<<NBLK2, 256, 0, stream>>>((const uint4*)sigS, out,
                                          (const float4*)bmin, (const float4*)bmax,
                                          partial);
    lasd_finish<<<1, 256, 0, stream>>>(partial, out);
}

// Round 10
// 42.280 us; speedup vs baseline: 1.1306x; 1.0859x over previous
//
#include <hip/hip_runtime.h>
#include <hip/hip_fp16.h>

#define NCLS 21
#define HW (512 * 512)
#define HW2 (HW / 2)                   // 131072 float2 per (b,c) plane
#define NB 8
#define NPIX (NB * HW)                 // 2097152
#define NPIX2 (NPIX / 2)               // 1048576 pixel-pairs
#define NPIX4 (NPIX / 4)               // 524288 pixel-quads
#define NBLK1 (NPIX2 / 256)            // 4096 blocks pass1
#define NBLK2 (NPIX4 / 256)            // 2048 blocks pass2
#define TOTAL_ELEMS ((long long)NPIX * NCLS)

// ws layout:
//   [0     .. 16K)  float bmin[4096]
//   [16K   .. 32K)  float bmax[4096]
//   [32K   .. 48K)  double partial[2048]
//   [64K   .. +8MB) packed half2 per pixel (x=sigma_raw fp16, y=S fp16)

union HU { __half2 h; unsigned int u; };

// Pass 1: single logits read; softmax stats + focal; packed (sig,S) fp16;
// per-block min/max partials. No atomics, no fences.  [proven 41.8 us]
__global__ __launch_bounds__(256) void lasd_pass1(const float2* __restrict__ in2,
                                                  const int2* __restrict__ tgt2,
                                                  uint2* __restrict__ sigS2,
                                                  float* __restrict__ bmin,
                                                  float* __restrict__ bmax) {
    int j = blockIdx.x * 256 + threadIdx.x;    // pixel-pair index
    int b = j >> 17;                            // j / HW2
    int p2 = j & (HW2 - 1);
    const float2* base = in2 + ((size_t)(b * NCLS) << 17) + p2;

    int2 tt = tgt2[j];                          // independent load, issue early

    float2 x[NCLS];
#pragma unroll
    for (int c = 0; c < NCLS; ++c) x[c] = base[(size_t)c << 17];

    float s0 = 0.f, s1 = 0.f;
#pragma unroll
    for (int c = 0; c < NCLS; ++c) { s0 += __expf(x[c].x); s1 += __expf(x[c].y); }
    float inv0 = 1.0f / s0, inv1 = 1.0f / s1;
    float ls0 = __logf(s0), ls1 = __logf(s1);

    float sp0 = 0, sp1 = 0, q0 = 0, q1 = 0, F0 = 0, F1 = 0, ft0 = 0, ft1 = 0;
#pragma unroll
    for (int c = 0; c < NCLS; ++c) {
        float p0 = __expf(x[c].x) * inv0 + 1e-8f;        // softmax + EPS
        float p1 = __expf(x[c].y) * inv1 + 1e-8f;
        float om0 = 1.0f - p0, om1 = 1.0f - p1;
        float f0 = -0.25f * om0 * om0 * (x[c].x - ls0);  // log p = x - log s
        float f1 = -0.25f * om1 * om1 * (x[c].y - ls1);
        sp0 += p0; sp1 += p1;
        q0 = fmaf(p0, p0, q0); q1 = fmaf(p1, p1, q1);
        F0 += f0; F1 += f1;
        if (c == tt.x) ft0 = f0;
        if (c == tt.y) ft1 = f1;
    }

    float var0 = fmaxf(q0 - sp0 * sp0 * (1.0f / 21.0f), 0.0f);
    float var1 = fmaxf(q1 - sp1 * sp1 * (1.0f / 21.0f), 0.0f);
    float sg0 = sqrtf(var0 * (1.0f / 20.0f));            // ddof=1
    float sg1 = sqrtf(var1 * (1.0f / 20.0f));
    float S0 = ft0 + 1e-6f * F0;
    float S1 = ft1 + 1e-6f * F1;

    HU h0, h1;
    h0.h.x = __float2half_rn(sg0); h0.h.y = __float2half_rn(S0);
    h1.h.x = __float2half_rn(sg1); h1.h.y = __float2half_rn(S1);
    uint2 pk; pk.x = h0.u; pk.y = h1.u;
    sigS2[j] = pk;

    // min/max over the ROUNDED sigmas (consistent with what pass2 reads)
    float r0 = __half2float(h0.h.x), r1 = __half2float(h1.h.x);
    float lmin = fminf(r0, r1), lmax = fmaxf(r0, r1);
#pragma unroll
    for (int off = 32; off > 0; off >>= 1) {
        lmin = fminf(lmin, __shfl_down(lmin, off));
        lmax = fmaxf(lmax, __shfl_down(lmax, off));
    }
    __shared__ float smn[4], smx[4];
    int wid = threadIdx.x >> 6, lane = threadIdx.x & 63;
    if (lane == 0) { smn[wid] = lmin; smx[wid] = lmax; }
    __syncthreads();
    if (threadIdx.x == 0) {
        bmin[blockIdx.x] = fminf(fminf(smn[0], smn[1]), fminf(smn[2], smn[3]));
        bmax[blockIdx.x] = fmaxf(fmaxf(smx[0], smx[1]), fmaxf(smx[2], smx[3]));
    }
}

// Pass 2: redundant per-block min/max reduce (L2/L3-served, no fence);
// normalize sigma -> out; per-block beta*S partial sums.
__global__ __launch_bounds__(256) void lasd_pass2(const uint4* __restrict__ sigS4,
                                                  float* __restrict__ out,     // [1..] sigma
                                                  const float4* __restrict__ bmin4,
                                                  const float4* __restrict__ bmax4,
                                                  double* __restrict__ partial) {
    const int wid = threadIdx.x >> 6, lane = threadIdx.x & 63;

    float a = 1e30f, z = -1e30f;
#pragma unroll
    for (int k = 0; k < NBLK1 / 4 / 256; ++k) {          // 4096 floats = 1024 float4
        float4 v = bmin4[threadIdx.x + k * 256];
        float4 w = bmax4[threadIdx.x + k * 256];
        a = fminf(a, fminf(fminf(v.x, v.y), fminf(v.z, v.w)));
        z = fmaxf(z, fmaxf(fmaxf(w.x, w.y), fmaxf(w.z, w.w)));
    }
#pragma unroll
    for (int off = 32; off > 0; off >>= 1) {
        a = fminf(a, __shfl_down(a, off));
        z = fmaxf(z, __shfl_down(z, off));
    }
    __shared__ float smn[4], smx[4];
    __shared__ float s_min, s_rinv;
    if (lane == 0) { smn[wid] = a; smx[wid] = z; }
    __syncthreads();
    if (threadIdx.x == 0) {
        float mn = fminf(fminf(smn[0], smn[1]), fminf(smn[2], smn[3]));
        float mx = fmaxf(fmaxf(smx[0], smx[1]), fmaxf(smx[2], smx[3]));
        s_min = mn;
        s_rinv = 1.0f / (mx - mn);
    }
    __syncthreads();
    float smin = s_min, rinv = s_rinv;

    int j = blockIdx.x * 256 + threadIdx.x;              // pixel-quad index
    uint4 pk = sigS4[j];
    unsigned int w[4] = {pk.x, pk.y, pk.z, pk.w};
    float lsum = 0.0f;
#pragma unroll
    for (int k = 0; k < 4; ++k) {
        HU cv; cv.u = w[k];
        float sg = __half2float(cv.h.x);
        float S = __half2float(cv.h.y);
        float t = (sg - smin) * rinv;
        out[1 + 4 * j + k] = t;
        lsum += (__expf(-t) + 1.0f) * S;
    }
#pragma unroll
    for (int off = 32; off > 0; off >>= 1) lsum += __shfl_down(lsum, off);
    __shared__ float shs[4];
    if (lane == 0) shs[wid] = lsum;
    __syncthreads();
    if (threadIdx.x == 0)
        partial[blockIdx.x] = (double)(shs[0] + shs[1] + shs[2] + shs[3]);
}

// Final: sum 2048 doubles -> loss
__global__ __launch_bounds__(256) void lasd_finish(const double* __restrict__ partial,
                                                   float* __restrict__ loss_out) {
    double acc = 0.0;
#pragma unroll
    for (int k = 0; k < NBLK2 / 256; ++k)
        acc += partial[threadIdx.x + k * 256];
#pragma unroll
    for (int off = 32; off > 0; off >>= 1) acc += __shfl_down(acc, off);
    __shared__ double sh[4];
    int wid = threadIdx.x >> 6, lane = threadIdx.x & 63;
    if (lane == 0) sh[wid] = acc;
    __syncthreads();
    if (threadIdx.x == 0)
        loss_out[0] = (float)((sh[0] + sh[1] + sh[2] + sh[3]) / (double)TOTAL_ELEMS);
}

extern "C" void kernel_launch(void* const* d_in, const int* in_sizes, int n_in,
                              void* d_out, int out_size, void* d_ws, size_t ws_size,
                              hipStream_t stream) {
    const float2* logits2 = (const float2*)d_in[0];
    const int2* target2 = (const int2*)d_in[1];
    float* out = (float*)d_out;                  // out[0]=loss, out[1..]=sigma
    char* ws = (char*)d_ws;

    float* bmin = (float*)ws;                    // 4096 f
    float* bmax = (float*)(ws + 16384);          // 4096 f
    double* partial = (double*)(ws + 32768);     // 2048 d
    uint2* sigS = (uint2*)(ws + 65536);          // 8 MB packed

    lasd_pass1<<<NBLK1, 256, 0, stream>>>(logits2, target2, sigS, bmin, bmax);
    lasd_pass2<<<NBLK2, 256, 0, stream>>>((const uint4*)sigS, out,
                                          (const float4*)bmin, (const float4*)bmax,
                                          partial);
    lasd_finish<<<1, 256, 0, stream>>>(partial, out);
}